// Round 3
// baseline (269.260 us; speedup 1.0000x reference)
//
#include <hip/hip_runtime.h>

// ---------------------------------------------------------------------------
// DensityMatrixMLP: out[b] = (L Lt) / trace(L Lt),  L = tril(relu(x@W1+b1)@W2+b2)
// B=131072, IN=256, HID=128, TRIL=136, D=16.
//
// R2 post-mortem: peak regs = 64 VGPR + 72 AGPR (acc2) = 136 -> 3 waves/SIMD
// (occupancy 38%), latency-bound everywhere (BW 29%, VALU 12%, MFMA 6%).
// R3: one 16-row m-tile per wave (BM=64): acc1=32, acc2=36 AGPR, peak ~100 regs
// -> launch_bounds(256,5) = 5 waves/SIMD = 20 waves/CU. All LDS is wave-private
// (per-wave 5120B chunk, hbuf/lv overlaid) -> ZERO barriers in the kernel.
// ---------------------------------------------------------------------------

typedef _Float16 h8 __attribute__((ext_vector_type(8)));
typedef float    f4 __attribute__((ext_vector_type(4)));
typedef int      i2 __attribute__((ext_vector_type(2)));

#define BATCH_N 131072
#define IN_DIM  256
#define HID     128
#define TRILN   136
#define BM      64       // batch rows per block: 4 waves x ONE 16-row m-tile
#define NT1     8        // 128/16 n-tiles, GEMM1
#define KS1     8        // 256/32 k-steps, GEMM1
#define NT2     9        // ceil(136/16) n-tiles, GEMM2 (padded with zeros)
#define KS2     4        // 128/32 k-steps, GEMM2
#define HSTR    136      // h row stride (halves): 272B, 16B-aligned rows
#define LVSTR   160      // padded-tril row stride (halves): rows 4-half aligned
#define CHUNKH  (16*LVSTR)          // per-wave LDS chunk, halves (5120 B)
#define PW1_N   (KS1*NT1*64*8)      // 32768 halves = 64 KB
#define PW2_N   (KS2*NT2*64*8)      // 18432 halves = 36 KB

// offset (halves) of tril row i inside a batch row's LVSTR region
// (rows padded to 4*ceil((i+1)/4))
__device__ __forceinline__ int rowoff(int i) {
    int g = i >> 2;
    return 4 * (g + 1) * (2 * g + (i & 3));   // 0,4,8,...,144
}

// ---------------------------------------------------------------------------
// Prelude: pack W1/W2 into MFMA B-fragment order, fp16.
// B-frag of mfma_16x16x32_f16: lane holds B[k=(lane>>4)*8+j][n=lane&15], j=0..7.
// ---------------------------------------------------------------------------
__global__ void pack_weights(const float* __restrict__ W1,
                             const float* __restrict__ W2,
                             _Float16* __restrict__ pw1,
                             _Float16* __restrict__ pw2) {
    int gid = blockIdx.x * blockDim.x + threadIdx.x;
    if (gid < PW1_N) {
        int j = gid & 7, l = (gid >> 3) & 63, f = gid >> 9;
        int ks = f >> 3, nt = f & 7;
        int k = ks * 32 + (l >> 4) * 8 + j;
        int n = nt * 16 + (l & 15);
        pw1[gid] = (_Float16)W1[k * HID + n];
    } else if (gid < PW1_N + PW2_N) {
        int g = gid - PW1_N;
        int j = g & 7, l = (g >> 3) & 63, f = g >> 9;
        int ks = f / NT2, nt = f - ks * NT2;
        int k = ks * 32 + (l >> 4) * 8 + j;
        int col = nt * 16 + (l & 15);
        pw2[g] = (col < TRILN) ? (_Float16)W2[k * TRILN + col] : (_Float16)0.0f;
    }
}

__device__ __forceinline__ h8 cvt_h8(f4 lo, f4 hi) {
    h8 r;
    r[0] = (_Float16)lo[0]; r[1] = (_Float16)lo[1];
    r[2] = (_Float16)lo[2]; r[3] = (_Float16)lo[3];
    r[4] = (_Float16)hi[0]; r[5] = (_Float16)hi[1];
    r[6] = (_Float16)hi[2]; r[7] = (_Float16)hi[3];
    return r;
}

// ---------------------------------------------------------------------------
// Fused kernel: 256 threads (4 fully independent waves), 64 batch rows/block,
// NO barriers. Each wave: 16-row GEMM1 -> LDS(h, private) -> GEMM2 ->
// scatter v (fp16, private lv) -> LL^T via MFMA (A-frag == B-frag identity).
// ---------------------------------------------------------------------------
__global__ __launch_bounds__(256, 5) void fused_mlp(
        const float* __restrict__ x, const float* __restrict__ b1,
        const float* __restrict__ b2, const _Float16* __restrict__ pw1,
        const _Float16* __restrict__ pw2, float* __restrict__ out) {
    __shared__ _Float16 smem[4 * CHUNKH] __attribute__((aligned(16)));  // 20480 B

    const int tid  = threadIdx.x;
    const int w    = tid >> 6;
    const int lane = tid & 63;
    const int q    = lane >> 4;
    const int lm   = lane & 15;
    const int b0   = blockIdx.x * BM;

    _Float16* hbuf = smem + w * CHUNKH;   // [16][HSTR]  (GEMM1 -> GEMM2)
    _Float16* lv   = smem + w * CHUNKH;   // [16][LVSTR] (overlaid, wave-private)

    // ---------------- GEMM1: h = relu(x @ W1 + b1) ----------------
    f4 acc1[NT1];
    #pragma unroll
    for (int nt = 0; nt < NT1; ++nt) acc1[nt] = (f4){0.f, 0.f, 0.f, 0.f};

    const float* xr0 = x + (size_t)(b0 + w * 16 + lm) * IN_DIM + q * 8;
    f4 a0l = *(const f4*)xr0, a0h = *(const f4*)(xr0 + 4);

    #pragma unroll
    for (int ks = 0; ks < KS1; ++ks) {
        h8 bf[NT1];
        #pragma unroll
        for (int nt = 0; nt < NT1; ++nt)
            bf[nt] = *(const h8*)(pw1 + ((ks * NT1 + nt) * 64 + lane) * 8);
        h8 af0 = cvt_h8(a0l, a0h);
        if (ks + 1 < KS1) {  // prefetch next k-step of x (the HBM stream)
            const float* p0 = xr0 + (ks + 1) * 32;
            a0l = *(const f4*)p0; a0h = *(const f4*)(p0 + 4);
        }
        #pragma unroll
        for (int nt = 0; nt < NT1; ++nt)
            acc1[nt] = __builtin_amdgcn_mfma_f32_16x16x32_f16(af0, bf[nt], acc1[nt], 0, 0, 0);
    }

    // bias + relu + store h to private LDS rows (no barrier needed)
    {
        float b1v[NT1];
        #pragma unroll
        for (int nt = 0; nt < NT1; ++nt) b1v[nt] = b1[nt * 16 + lm];
        #pragma unroll
        for (int nt = 0; nt < NT1; ++nt)
            #pragma unroll
            for (int r = 0; r < 4; ++r) {
                float hv = fmaxf(acc1[nt][r] + b1v[nt], 0.f);
                hbuf[(q * 4 + r) * HSTR + nt * 16 + lm] = (_Float16)hv;  // C-layout
            }
    }

    // ---------------- GEMM2: v = h @ W2 + b2 ----------------
    f4 acc2[NT2];
    #pragma unroll
    for (int nt = 0; nt < NT2; ++nt) acc2[nt] = (f4){0.f, 0.f, 0.f, 0.f};

    // A-frags for all 4 k-steps (wave-private rows; compiler orders via lgkmcnt)
    h8 ha[KS2];
    #pragma unroll
    for (int ks = 0; ks < KS2; ++ks)
        ha[ks] = *(const h8*)(hbuf + lm * HSTR + ks * 32 + q * 8);

    #pragma unroll
    for (int nt = 0; nt < NT2; ++nt) {
        #pragma unroll
        for (int ks = 0; ks < KS2; ++ks) {
            h8 bf = *(const h8*)(pw2 + ((ks * NT2 + nt) * 64 + lane) * 8);
            acc2[nt] = __builtin_amdgcn_mfma_f32_16x16x32_f16(ha[ks], bf, acc2[nt], 0, 0, 0);
        }
    }

    float b2v[NT2];
    #pragma unroll
    for (int nt = 0; nt < NT2; ++nt) {
        int col = nt * 16 + lm;
        b2v[nt] = (col < TRILN) ? b2[col] : 0.f;
    }

    // trace partials from registers; reduce across the 16 lanes of each row
    float rinv[4];
    {
        float ps[4] = {0.f, 0.f, 0.f, 0.f};
        #pragma unroll
        for (int nt = 0; nt < NT2; ++nt)
            #pragma unroll
            for (int r = 0; r < 4; ++r) {
                float v = acc2[nt][r] + b2v[nt];   // cols>=136 contribute 0
                ps[r] += v * v;
            }
        #pragma unroll
        for (int r = 0; r < 4; ++r) {
            float s = ps[r];
            s += __shfl_xor(s, 1);
            s += __shfl_xor(s, 2);
            s += __shfl_xor(s, 4);
            s += __shfl_xor(s, 8);
            rinv[r] = 1.0f / s;
        }
    }

    // per-lane tril mapping for the 9 columns this lane owns: col c -> (i,k)
    int voff[NT2];
    bool vok[NT2];
    #pragma unroll
    for (int nt = 0; nt < NT2; ++nt) {
        int c = nt * 16 + lm;
        vok[nt] = (c < TRILN);
        int cc = vok[nt] ? c : 0;
        int i = (int)((sqrtf(8.0f * (float)cc + 1.0f) - 1.0f) * 0.5f);
        int k = cc - (i * (i + 1)) / 2;
        voff[nt] = rowoff(i) + k;
    }

    // scatter v (fp16) into padded-tril layout (private region, no barrier)
    #pragma unroll
    for (int r = 0; r < 4; ++r) {
        int base = (q * 4 + r) * LVSTR;
        #pragma unroll
        for (int nt = 0; nt < NT2; ++nt)
            if (vok[nt])
                lv[base + voff[nt]] = (_Float16)(acc2[nt][r] + b2v[nt]);
    }

    // frag masks: element j is L[lm][q*8+j], valid iff q*8+j <= lm
    int msk[4];
    {
        int n = lm - q * 8 + 1;
        #pragma unroll
        for (int p = 0; p < 4; ++p) {
            int c2 = n - 2 * p; c2 = c2 < 0 ? 0 : (c2 > 2 ? 2 : c2);
            msk[p] = (c2 == 2) ? ~0 : ((c2 == 1) ? 0xFFFF : 0);
        }
    }
    const int ro_lm = rowoff(lm);
    const f4 zero = (f4){0.f, 0.f, 0.f, 0.f};
    const int outcol = q * 64 + lm;

    // ---------------- LL^T via MFMA: one frag per batch row ----------------
    #pragma unroll
    for (int tq = 0; tq < 4; ++tq)
        #pragma unroll
        for (int r4 = 0; r4 < 4; ++r4) {
            int t = tq * 4 + r4;
            const _Float16* rp = lv + t * LVSTR + ro_lm + q * 8;
            i2 lo = *(const i2*)rp;
            i2 hi = *(const i2*)(rp + 4);
            h8 frag;
            ((i2*)&frag)[0] = (i2){lo.x & msk[0], lo.y & msk[1]};
            ((i2*)&frag)[1] = (i2){hi.x & msk[2], hi.y & msk[3]};
            f4 d = __builtin_amdgcn_mfma_f32_16x16x32_f16(frag, frag, zero, 0, 0, 0);
            float riv = __uint_as_float(
                __builtin_amdgcn_readlane(__float_as_uint(rinv[r4]), tq * 16));
            float* op = out + (size_t)(b0 + w * 16 + t) * 256 + outcol;
            #pragma unroll
            for (int sr = 0; sr < 4; ++sr)
                op[sr * 16] = d[sr] * riv;   // 4x64B sectors per instr
        }
}

extern "C" void kernel_launch(void* const* d_in, const int* in_sizes, int n_in,
                              void* d_out, int out_size, void* d_ws, size_t ws_size,
                              hipStream_t stream) {
    const float* x  = (const float*)d_in[0];
    const float* W1 = (const float*)d_in[1];
    const float* b1 = (const float*)d_in[2];
    const float* W2 = (const float*)d_in[3];
    const float* b2 = (const float*)d_in[4];
    float* out = (float*)d_out;

    _Float16* pw1 = (_Float16*)d_ws;            // 64 KB
    _Float16* pw2 = pw1 + PW1_N;                // 36 KB  (needs ws_size >= 100 KB)

    pack_weights<<<(PW1_N + PW2_N + 255) / 256, 256, 0, stream>>>(W1, W2, pw1, pw2);
    fused_mlp<<<BATCH_N / BM, 256, 0, stream>>>(x, b1, b2, pw1, pw2, out);
}

// Round 4
// 264.888 us; speedup vs baseline: 1.0165x; 1.0165x over previous
//
#include <hip/hip_runtime.h>

// ---------------------------------------------------------------------------
// DensityMatrixMLP: out[b] = (L Lt) / trace(L Lt),  L = tril(relu(x@W1+b1)@W2+b2)
// B=131072, IN=256, HID=128, TRIL=136, D=16.
//
// R3 post-mortem: every pipe <25% busy at any occupancy/reg budget -> the
// bottleneck is memory-level parallelism: reg-squeezed code convoys loads
// (~2 in flight/wave x 13 waves/CU ~= 26 lines outstanding -> 2 B/cyc/CU,
// matching measured 202MB/254k cyc). R4: issue ALL 16 x-loads (the HBM
// stream) upfront into 64 VGPRs, cvt to fp16, free them; launch_bounds
// (256,3) gives the scheduler room to pipeline weight loads too.
// ---------------------------------------------------------------------------

typedef _Float16 h8 __attribute__((ext_vector_type(8)));
typedef float    f4 __attribute__((ext_vector_type(4)));
typedef int      i2 __attribute__((ext_vector_type(2)));

#define BATCH_N 131072
#define IN_DIM  256
#define HID     128
#define TRILN   136
#define BM      64       // batch rows per block: 4 waves x ONE 16-row m-tile
#define NT1     8        // 128/16 n-tiles, GEMM1
#define KS1     8        // 256/32 k-steps, GEMM1
#define NT2     9        // ceil(136/16) n-tiles, GEMM2 (padded with zeros)
#define KS2     4        // 128/32 k-steps, GEMM2
#define HSTR    136      // h row stride (halves): 272B, 16B-aligned rows
#define LVSTR   160      // padded-tril row stride (halves): rows 4-half aligned
#define CHUNKH  (16*LVSTR)          // per-wave LDS chunk, halves (5120 B)
#define PW1_N   (KS1*NT1*64*8)      // 32768 halves = 64 KB
#define PW2_N   (KS2*NT2*64*8)      // 18432 halves = 36 KB

// offset (halves) of tril row i inside a batch row's LVSTR region
__device__ __forceinline__ int rowoff(int i) {
    int g = i >> 2;
    return 4 * (g + 1) * (2 * g + (i & 3));   // 0,4,8,...,144
}

// ---------------------------------------------------------------------------
// Prelude: pack W1/W2 into MFMA B-fragment order, fp16.
// B-frag of mfma_16x16x32_f16: lane holds B[k=(lane>>4)*8+j][n=lane&15], j=0..7.
// ---------------------------------------------------------------------------
__global__ void pack_weights(const float* __restrict__ W1,
                             const float* __restrict__ W2,
                             _Float16* __restrict__ pw1,
                             _Float16* __restrict__ pw2) {
    int gid = blockIdx.x * blockDim.x + threadIdx.x;
    if (gid < PW1_N) {
        int j = gid & 7, l = (gid >> 3) & 63, f = gid >> 9;
        int ks = f >> 3, nt = f & 7;
        int k = ks * 32 + (l >> 4) * 8 + j;
        int n = nt * 16 + (l & 15);
        pw1[gid] = (_Float16)W1[k * HID + n];
    } else if (gid < PW1_N + PW2_N) {
        int g = gid - PW1_N;
        int j = g & 7, l = (g >> 3) & 63, f = g >> 9;
        int ks = f / NT2, nt = f - ks * NT2;
        int k = ks * 32 + (l >> 4) * 8 + j;
        int col = nt * 16 + (l & 15);
        pw2[g] = (col < TRILN) ? (_Float16)W2[k * TRILN + col] : (_Float16)0.0f;
    }
}

__device__ __forceinline__ h8 cvt_h8(f4 lo, f4 hi) {
    h8 r;
    r[0] = (_Float16)lo[0]; r[1] = (_Float16)lo[1];
    r[2] = (_Float16)lo[2]; r[3] = (_Float16)lo[3];
    r[4] = (_Float16)hi[0]; r[5] = (_Float16)hi[1];
    r[6] = (_Float16)hi[2]; r[7] = (_Float16)hi[3];
    return r;
}

// ---------------------------------------------------------------------------
// Fused kernel: 256 threads (4 independent waves), 64 batch rows/block,
// NO barriers. Wave: prefetch whole x-tile -> GEMM1 -> LDS(h, private) ->
// GEMM2 -> scatter v -> LL^T via MFMA (A-frag == B-frag identity).
// ---------------------------------------------------------------------------
__global__ __launch_bounds__(256, 3) void fused_mlp(
        const float* __restrict__ x, const float* __restrict__ b1,
        const float* __restrict__ b2, const _Float16* __restrict__ pw1,
        const _Float16* __restrict__ pw2, float* __restrict__ out) {
    __shared__ _Float16 smem[4 * CHUNKH] __attribute__((aligned(16)));  // 20480 B

    const int tid  = threadIdx.x;
    const int w    = tid >> 6;
    const int lane = tid & 63;
    const int q    = lane >> 4;
    const int lm   = lane & 15;
    const int b0   = blockIdx.x * BM;

    _Float16* hbuf = smem + w * CHUNKH;   // [16][HSTR]  (GEMM1 -> GEMM2)
    _Float16* lv   = smem + w * CHUNKH;   // [16][LVSTR] (overlaid, wave-private)

    // ---- prefetch the ENTIRE x m-tile: 16 dwordx4 issued back-to-back ----
    // (this is the HBM stream; 16 outstanding loads/wave is the MLP we need)
    const float* xp = x + (size_t)(b0 + w * 16 + lm) * IN_DIM + q * 8;
    f4 xa[2 * KS1];
    #pragma unroll
    for (int ks = 0; ks < KS1; ++ks) {
        xa[2 * ks]     = *(const f4*)(xp + ks * 32);
        xa[2 * ks + 1] = *(const f4*)(xp + ks * 32 + 4);
    }
    // convert to fp16 frags (frees the 64 fp32 VGPRs)
    h8 xh[KS1];
    #pragma unroll
    for (int ks = 0; ks < KS1; ++ks)
        xh[ks] = cvt_h8(xa[2 * ks], xa[2 * ks + 1]);

    // ---------------- GEMM1: h = relu(x @ W1 + b1) ----------------
    f4 acc1[NT1];
    #pragma unroll
    for (int nt = 0; nt < NT1; ++nt) acc1[nt] = (f4){0.f, 0.f, 0.f, 0.f};

    #pragma unroll
    for (int ks = 0; ks < KS1; ++ks) {
        h8 bf[NT1];
        #pragma unroll
        for (int nt = 0; nt < NT1; ++nt)
            bf[nt] = *(const h8*)(pw1 + ((ks * NT1 + nt) * 64 + lane) * 8);
        #pragma unroll
        for (int nt = 0; nt < NT1; ++nt)
            acc1[nt] = __builtin_amdgcn_mfma_f32_16x16x32_f16(xh[ks], bf[nt], acc1[nt], 0, 0, 0);
    }

    // bias + relu + store h to private LDS rows (no barrier needed)
    {
        float b1v[NT1];
        #pragma unroll
        for (int nt = 0; nt < NT1; ++nt) b1v[nt] = b1[nt * 16 + lm];
        #pragma unroll
        for (int nt = 0; nt < NT1; ++nt)
            #pragma unroll
            for (int r = 0; r < 4; ++r) {
                float hv = fmaxf(acc1[nt][r] + b1v[nt], 0.f);
                hbuf[(q * 4 + r) * HSTR + nt * 16 + lm] = (_Float16)hv;  // C-layout
            }
    }

    // ---------------- GEMM2: v = h @ W2 + b2 ----------------
    f4 acc2[NT2];
    #pragma unroll
    for (int nt = 0; nt < NT2; ++nt) acc2[nt] = (f4){0.f, 0.f, 0.f, 0.f};

    h8 ha[KS2];
    #pragma unroll
    for (int ks = 0; ks < KS2; ++ks)
        ha[ks] = *(const h8*)(hbuf + lm * HSTR + ks * 32 + q * 8);

    #pragma unroll
    for (int nt = 0; nt < NT2; ++nt) {
        #pragma unroll
        for (int ks = 0; ks < KS2; ++ks) {
            h8 bf = *(const h8*)(pw2 + ((ks * NT2 + nt) * 64 + lane) * 8);
            acc2[nt] = __builtin_amdgcn_mfma_f32_16x16x32_f16(ha[ks], bf, acc2[nt], 0, 0, 0);
        }
    }

    float b2v[NT2];
    #pragma unroll
    for (int nt = 0; nt < NT2; ++nt) {
        int col = nt * 16 + lm;
        b2v[nt] = (col < TRILN) ? b2[col] : 0.f;
    }

    // trace partials from registers; reduce across the 16 lanes of each row
    float rinv[4];
    {
        float ps[4] = {0.f, 0.f, 0.f, 0.f};
        #pragma unroll
        for (int nt = 0; nt < NT2; ++nt)
            #pragma unroll
            for (int r = 0; r < 4; ++r) {
                float v = acc2[nt][r] + b2v[nt];   // cols>=136 contribute 0
                ps[r] += v * v;
            }
        #pragma unroll
        for (int r = 0; r < 4; ++r) {
            float s = ps[r];
            s += __shfl_xor(s, 1);
            s += __shfl_xor(s, 2);
            s += __shfl_xor(s, 4);
            s += __shfl_xor(s, 8);
            rinv[r] = 1.0f / s;
        }
    }

    // per-lane tril mapping for the 9 columns this lane owns: col c -> (i,k)
    int voff[NT2];
    bool vok[NT2];
    #pragma unroll
    for (int nt = 0; nt < NT2; ++nt) {
        int c = nt * 16 + lm;
        vok[nt] = (c < TRILN);
        int cc = vok[nt] ? c : 0;
        int i = (int)((sqrtf(8.0f * (float)cc + 1.0f) - 1.0f) * 0.5f);
        int k = cc - (i * (i + 1)) / 2;
        voff[nt] = rowoff(i) + k;
    }

    // scatter v (fp16) into padded-tril layout (private region, no barrier)
    #pragma unroll
    for (int r = 0; r < 4; ++r) {
        int base = (q * 4 + r) * LVSTR;
        #pragma unroll
        for (int nt = 0; nt < NT2; ++nt)
            if (vok[nt])
                lv[base + voff[nt]] = (_Float16)(acc2[nt][r] + b2v[nt]);
    }

    // frag masks: element j is L[lm][q*8+j], valid iff q*8+j <= lm
    int msk[4];
    {
        int n = lm - q * 8 + 1;
        #pragma unroll
        for (int p = 0; p < 4; ++p) {
            int c2 = n - 2 * p; c2 = c2 < 0 ? 0 : (c2 > 2 ? 2 : c2);
            msk[p] = (c2 == 2) ? ~0 : ((c2 == 1) ? 0xFFFF : 0);
        }
    }
    const int ro_lm = rowoff(lm);
    const f4 zero = (f4){0.f, 0.f, 0.f, 0.f};
    const int outcol = q * 64 + lm;

    // ---------------- LL^T via MFMA: one frag per batch row ----------------
    #pragma unroll
    for (int tq = 0; tq < 4; ++tq)
        #pragma unroll
        for (int r4 = 0; r4 < 4; ++r4) {
            int t = tq * 4 + r4;
            const _Float16* rp = lv + t * LVSTR + ro_lm + q * 8;
            i2 lo = *(const i2*)rp;
            i2 hi = *(const i2*)(rp + 4);
            h8 frag;
            ((i2*)&frag)[0] = (i2){lo.x & msk[0], lo.y & msk[1]};
            ((i2*)&frag)[1] = (i2){hi.x & msk[2], hi.y & msk[3]};
            f4 d = __builtin_amdgcn_mfma_f32_16x16x32_f16(frag, frag, zero, 0, 0, 0);
            float riv = __uint_as_float(
                __builtin_amdgcn_readlane(__float_as_uint(rinv[r4]), tq * 16));
            float* op = out + (size_t)(b0 + w * 16 + t) * 256 + outcol;
            #pragma unroll
            for (int sr = 0; sr < 4; ++sr)
                op[sr * 16] = d[sr] * riv;   // 4x64B sectors per instr
        }
}

extern "C" void kernel_launch(void* const* d_in, const int* in_sizes, int n_in,
                              void* d_out, int out_size, void* d_ws, size_t ws_size,
                              hipStream_t stream) {
    const float* x  = (const float*)d_in[0];
    const float* W1 = (const float*)d_in[1];
    const float* b1 = (const float*)d_in[2];
    const float* W2 = (const float*)d_in[3];
    const float* b2 = (const float*)d_in[4];
    float* out = (float*)d_out;

    _Float16* pw1 = (_Float16*)d_ws;            // 64 KB
    _Float16* pw2 = pw1 + PW1_N;                // 36 KB  (needs ws_size >= 100 KB)

    pack_weights<<<(PW1_N + PW2_N + 255) / 256, 256, 0, stream>>>(W1, W2, pw1, pw2);
    fused_mlp<<<BATCH_N / BM, 256, 0, stream>>>(x, b1, b2, pw1, pw2, out);
}